// Round 3
// baseline (1761.851 us; speedup 1.0000x reference)
//
#include <hip/hip_runtime.h>
#include <hip/hip_bf16.h>

#define DCH 64
#define NB_CSR 256          // edge-chunk blocks; chunk = ceil(e/256)
#define MAXBINS 512         // bins = ceil(n/128); n<=65536
#define BINN 128            // nodes per bin (bin = col>>7)

typedef __attribute__((ext_vector_type(8))) short bfrag;   // 8 bf16
typedef __attribute__((ext_vector_type(4))) float ffrag;   // 4 fp32

static __device__ __forceinline__ unsigned short f2bf(float f) {
    unsigned u = __float_as_uint(f);
    unsigned r = (u + 0x7fffu + ((u >> 16) & 1u)) >> 16;   // RNE
    return (unsigned short)r;
}
static __device__ __forceinline__ float bf2f(unsigned short s) {
    return __uint_as_float(((unsigned)s) << 16);
}

// ---- CSR pass 1: per-block bin counts (bin = col>>7) ----
__global__ __launch_bounds__(1024) void binc_k(const int* __restrict__ col,
                                               unsigned* __restrict__ blkcnt, int e) {
    __shared__ unsigned bins[MAXBINS];
    int B = blockIdx.x, tid = threadIdx.x;
    int chunk = (e + NB_CSR - 1) / NB_CSR;
    int beg = B * chunk, end = min(e, beg + chunk);
    if (tid < MAXBINS) bins[tid] = 0;
    __syncthreads();
    for (int i = beg + tid; i < end; i += 1024)
        atomicAdd(&bins[col[i] >> 7], 1u);
    __syncthreads();
    if (tid < MAXBINS) blkcnt[B * MAXBINS + tid] = bins[tid];
}

// ---- CSR pass 2a (1 wave per bin): column prefix over the 256 chunk counts ----
__global__ __launch_bounds__(64) void bincur1_k(const unsigned* __restrict__ blkcnt,
                                                unsigned* __restrict__ blkcur,
                                                unsigned* __restrict__ tot) {
    int j = blockIdx.x, lane = threadIdx.x;
    unsigned carry = 0;
#pragma unroll
    for (int c = 0; c < NB_CSR; c += 64) {
        unsigned v = blkcnt[(size_t)(c + lane) * MAXBINS + j];
        unsigned s = v;
#pragma unroll
        for (int off = 1; off < 64; off <<= 1) {
            unsigned t = __shfl_up(s, off);
            if (lane >= off) s += t;
        }
        blkcur[(size_t)(c + lane) * MAXBINS + j] = carry + s - v;
        carry += __shfl(s, 63);
    }
    if (lane == 0) tot[j] = carry;
}

// ---- CSR pass 2b (1 block, 512 thr): exclusive scan of bin totals ----
__global__ __launch_bounds__(512) void bincur2_k(const unsigned* __restrict__ tot,
                                                 int* __restrict__ binbase,
                                                 int nbins, int e) {
    __shared__ int wtot[8];
    int tid = threadIdx.x, lane = tid & 63, w = tid >> 6;
    int v = (tid < nbins) ? (int)tot[tid] : 0;
    int s = v;
#pragma unroll
    for (int off = 1; off < 64; off <<= 1) {
        int t = __shfl_up(s, off);
        if (lane >= off) s += t;
    }
    if (lane == 63) wtot[w] = s;
    __syncthreads();
    if (tid == 0) {
        int r = 0;
#pragma unroll
        for (int k = 0; k < 8; ++k) { int t = wtot[k]; wtot[k] = r; r += t; }
    }
    __syncthreads();
    int excl = s - v + wtot[w];
    if (tid < nbins) binbase[tid] = excl;
    if (tid == 0) binbase[nbins] = e;
}

// ---- CSR pass 3: scatter packed records to bins (runs at block cursors) ----
// rec.x = src | ((tgt&127) << 20), rec.y = edge weight (later folded *dis[src])
__global__ __launch_bounds__(1024) void binfill_k(const int* __restrict__ row,
                                                  const int* __restrict__ col,
                                                  const float* __restrict__ ew,
                                                  const unsigned* __restrict__ blkcur,
                                                  const int* __restrict__ binbase,
                                                  uint2* __restrict__ rec, int e) {
    __shared__ unsigned cur[MAXBINS];
    int B = blockIdx.x, tid = threadIdx.x;
    int chunk = (e + NB_CSR - 1) / NB_CSR;
    int beg = B * chunk, end = min(e, beg + chunk);
    if (tid < MAXBINS) cur[tid] = blkcur[(size_t)B * MAXBINS + tid]
                                + (unsigned)binbase[tid];
    __syncthreads();
    for (int i = beg + tid; i < end; i += 1024) {
        int c = col[i];
        unsigned slot = atomicAdd(&cur[c >> 7], 1u);
        rec[slot] = make_uint2((unsigned)row[i] | ((unsigned)(c & 127) << 20),
                               __float_as_uint(ew[i]));
    }
}

// ---- deg pass (1 block per bin): deg sums + dis = rsqrt(deg + 2) ----
__global__ __launch_bounds__(512) void deg_k(const uint2* __restrict__ rec,
                                             const int* __restrict__ binbase,
                                             float* __restrict__ dis, int n) {
    __shared__ float degs[BINN];
    int tid = threadIdx.x, bin = blockIdx.x;
    if (tid < BINN) degs[tid] = 0.f;
    __syncthreads();
    int beg = binbase[bin], end = binbase[bin + 1];
    for (int i = beg + tid; i < end; i += 512) {
        uint2 r = rec[i];
        atomicAdd(&degs[r.x >> 20], __uint_as_float(r.y));
    }
    __syncthreads();
    int node0 = bin * BINN, nn = min(BINN, n - node0);
    if (tid < nn) dis[node0 + tid] = rsqrtf(degs[tid] + 2.0f);
}

// rec.y <- w * dis[src]  (fold source-side norm once, for all layers)
__global__ __launch_bounds__(256) void nfold_k(uint2* __restrict__ rec,
                                               const float* __restrict__ dis, int e) {
    int i = blockIdx.x * 256 + threadIdx.x;
    if (i >= e) return;
    uint2 r = rec[i];
    ((unsigned*)rec)[2 * i + 1] =
        __float_as_uint(__uint_as_float(r.y) * dis[r.x & 0xFFFFFu]);
}

// Pack W (all L layers) into MFMA B-fragment layout, bf16 hi/lo split.
__global__ __launch_bounds__(256) void pack_k(const float* __restrict__ Ws,
                                              short* __restrict__ wpk, int L) {
    int ent = blockIdx.x * 256 + threadIdx.x;
    if (ent >= L * 512) return;
    int layer = ent >> 9;
    int r = ent & 511;
    int lane = r & 63;
    int st = r >> 6;
    int s = st >> 2, t = st & 3;
    int quad = lane >> 4;
    int ncol = t * 16 + (lane & 15);
    const float* W = Ws + (size_t)layer * DCH * DCH;
    union { short sh[8]; int4 v; } hi, lo;
#pragma unroll
    for (int j = 0; j < 8; ++j) {
        int k = s * 32 + quad * 8 + j;
        float w = W[k * DCH + ncol];
        unsigned short h = f2bf(w);
        hi.sh[j] = (short)h;
        lo.sh[j] = (short)f2bf(w - bf2f(h));
    }
    *(int4*)(wpk + ((size_t)(layer * 2 + 0) * 512 + r) * 8) = hi.v;
    *(int4*)(wpk + ((size_t)(layer * 2 + 1) * 512 + r) * 8) = lo.v;
}

// layer-0 GEMM: h = x0 @ W0 via bf16-split MFMA; output bf16.
__global__ __launch_bounds__(256) void gemm_k(const float* __restrict__ x,
                                              const short* __restrict__ wpk_layer,
                                              unsigned short* __restrict__ hb, int n_tiles) {
    __shared__ short Wl[2][512 * 8];
    {
        const int4* src = (const int4*)wpk_layer;
        int4* dst = (int4*)&Wl[0][0];
        for (int i = threadIdx.x; i < 1024; i += 256) dst[i] = src[i];
    }
    __syncthreads();
    int wave = threadIdx.x >> 6, lane = threadIdx.x & 63;
    int tile = blockIdx.x * 4 + wave;
    if (tile >= n_tiles) return;
    int m = lane & 15, quad = lane >> 4;
    int row = tile * 16 + m;

    float av[2][8];
    {
        const float4* p0 = (const float4*)(x + (size_t)row * DCH + quad * 8);
        const float4* p1 = (const float4*)(x + (size_t)row * DCH + 32 + quad * 8);
        float4 a0 = p0[0], a1 = p0[1], b0 = p1[0], b1 = p1[1];
        av[0][0] = a0.x; av[0][1] = a0.y; av[0][2] = a0.z; av[0][3] = a0.w;
        av[0][4] = a1.x; av[0][5] = a1.y; av[0][6] = a1.z; av[0][7] = a1.w;
        av[1][0] = b0.x; av[1][1] = b0.y; av[1][2] = b0.z; av[1][3] = b0.w;
        av[1][4] = b1.x; av[1][5] = b1.y; av[1][6] = b1.z; av[1][7] = b1.w;
    }
    bfrag ah[2], al[2];
#pragma unroll
    for (int s = 0; s < 2; ++s)
#pragma unroll
        for (int j = 0; j < 8; ++j) {
            unsigned short hbv = f2bf(av[s][j]);
            ah[s][j] = (short)hbv;
            al[s][j] = (short)f2bf(av[s][j] - bf2f(hbv));
        }

#pragma unroll
    for (int t = 0; t < 4; ++t) {
        ffrag acc = {0.f, 0.f, 0.f, 0.f};
#pragma unroll
        for (int s = 0; s < 2; ++s) {
            bfrag wh = *(bfrag*)&Wl[0][((s * 4 + t) * 64 + lane) * 8];
            bfrag wl = *(bfrag*)&Wl[1][((s * 4 + t) * 64 + lane) * 8];
            acc = __builtin_amdgcn_mfma_f32_16x16x32_bf16(ah[s], wh, acc, 0, 0, 0);
            acc = __builtin_amdgcn_mfma_f32_16x16x32_bf16(al[s], wh, acc, 0, 0, 0);
            acc = __builtin_amdgcn_mfma_f32_16x16x32_bf16(ah[s], wl, acc, 0, 0, 0);
        }
        int colc = t * 16 + m;
#pragma unroll
        for (int r = 0; r < 4; ++r)
            hb[(size_t)(tile * 16 + quad * 4 + r) * DCH + colc] = f2bf(acc[r]);
    }
}

// ---- edge-scatter core: each half-wave owns one edge; lane c = channel pair
// (2c, 2c+1); rotated LDS layout ch' = (ch + 2*tgt) & 63 keeps every
// ds_add_f32 instruction exactly 2-way bank-aliased (free). ----
static __device__ __forceinline__ void scatter_edges(float* __restrict__ xs,
                                                     const uint2* __restrict__ rec,
                                                     int beg, int end, int w,
                                                     int hi, int c,
                                                     const unsigned* __restrict__ hbf) {
    int base = beg + 2 * w + hi;
    for (int i0 = base; i0 < end; i0 += 16 * 4) {
        uint2 rr[4]; unsigned hu[4];
#pragma unroll
        for (int u = 0; u < 4; ++u) {
            int idx = i0 + 16 * u;
            rr[u] = (idx < end) ? rec[idx] : make_uint2(0u, 0u);
        }
#pragma unroll
        for (int u = 0; u < 4; ++u)
            hu[u] = hbf[(size_t)(rr[u].x & 0xFFFFFu) * 32 + c];
#pragma unroll
        for (int u = 0; u < 4; ++u) {
            float wv = __uint_as_float(rr[u].y);          // pre-folded w*dis[src]
            int t = rr[u].x >> 20;
            float v0 = __uint_as_float(hu[u] << 16) * wv;          // ch 2c
            float v1 = __uint_as_float(hu[u] & 0xffff0000u) * wv;  // ch 2c+1
            int rb = (2 * c + 2 * t) & 63;                // even, no carry w/ +1
            atomicAdd(&xs[t * DCH + rb + hi],     hi ? v1 : v0);
            atomicAdd(&xs[t * DCH + rb + 1 - hi], hi ? v0 : v1);
        }
    }
}

// fused scatter-agg(l) + finalize + gemm(l+1): 1 block per 128-node bin.
__global__ __launch_bounds__(512) void sg_k(const uint2* __restrict__ rec,
                                            const int* __restrict__ binbase,
                                            const float* __restrict__ dis,
                                            const unsigned* __restrict__ hbf,
                                            const float* __restrict__ b,
                                            const short* __restrict__ wpk_next,
                                            unsigned short* __restrict__ hb_out, int n) {
    __shared__ float xs[BINN * DCH];          // 32 KB, rotated layout
    int tid = threadIdx.x, bin = blockIdx.x;
    for (int i = tid; i < BINN * DCH; i += 512) xs[i] = 0.f;
    __syncthreads();
    int beg = binbase[bin], end = binbase[bin + 1];
    int w = tid >> 6, lane = tid & 63;
    scatter_edges(xs, rec, beg, end, w, lane >> 5, lane & 31, hbf);
    __syncthreads();
    // ---- finalize: 4 threads/node; self-loop + dis*acc + bias + relu ----
    int slot = tid >> 2, cq = tid & 3;
    int node0 = bin * BINN;
    int nn = min(BINN, n - node0);
    if (slot < nn) {
        int node = node0 + slot;
        float dc = dis[node];
        float tl = 2.f * dc;
        const unsigned* hs = hbf + (size_t)node * 32 + cq * 8;
        const float2* b2 = (const float2*)b;
        int rot = 2 * slot;
#pragma unroll
        for (int j = 0; j < 8; ++j) {
            unsigned hv = hs[j];
            int ch = cq * 16 + 2 * j;
            int i0 = slot * DCH + ((ch + rot) & 63);
            int i1 = slot * DCH + ((ch + 1 + rot) & 63);
            float2 bv = b2[cq * 8 + j];
            float x0 = xs[i0] + tl * __uint_as_float(hv << 16);
            float x1 = xs[i1] + tl * __uint_as_float(hv & 0xffff0000u);
            xs[i0] = fmaxf(dc * x0 + bv.x, 0.f);
            xs[i1] = fmaxf(dc * x1 + bv.y, 0.f);
        }
    }
    __syncthreads();
    // ---- GEMM: wave w = tile w (16 rows), col-groups t=0..3 ----
    int m = lane & 15, quad = lane >> 4;
    int rowl = w * 16 + m;
    int rot = 2 * rowl;
    bfrag ah[2], al[2];
#pragma unroll
    for (int s = 0; s < 2; ++s)
#pragma unroll
        for (int j = 0; j < 8; ++j) {
            float v = xs[rowl * DCH + ((s * 32 + quad * 8 + j + rot) & 63)];
            unsigned short hbv = f2bf(v);
            ah[s][j] = (short)hbv;
            al[s][j] = (short)f2bf(v - bf2f(hbv));
        }
#pragma unroll
    for (int t = 0; t < 4; ++t) {
        ffrag acc = {0.f, 0.f, 0.f, 0.f};
#pragma unroll
        for (int s = 0; s < 2; ++s) {
            bfrag wh = *(const bfrag*)(wpk_next + ((size_t)((s * 4 + t) * 64 + lane)) * 8);
            bfrag wl = *(const bfrag*)(wpk_next + ((size_t)(512 + (s * 4 + t) * 64 + lane)) * 8);
            acc = __builtin_amdgcn_mfma_f32_16x16x32_bf16(ah[s], wh, acc, 0, 0, 0);
            acc = __builtin_amdgcn_mfma_f32_16x16x32_bf16(al[s], wh, acc, 0, 0, 0);
            acc = __builtin_amdgcn_mfma_f32_16x16x32_bf16(ah[s], wl, acc, 0, 0, 0);
        }
        int colc = t * 16 + m;
#pragma unroll
        for (int r = 0; r < 4; ++r) {
            int orow = node0 + w * 16 + quad * 4 + r;
            if (orow < n) hb_out[(size_t)orow * DCH + colc] = f2bf(acc[r]);
        }
    }
}

// fused scatter-agg(last) + finalize + final dot: out = relu-agg . Wf + bf
__global__ __launch_bounds__(512) void sf_k(const uint2* __restrict__ rec,
                                            const int* __restrict__ binbase,
                                            const float* __restrict__ dis,
                                            const unsigned* __restrict__ hbf,
                                            const float* __restrict__ b,
                                            const float* __restrict__ Wf,
                                            const float* __restrict__ bf,
                                            float* __restrict__ out, int n) {
    __shared__ float xs[BINN * DCH];
    int tid = threadIdx.x, bin = blockIdx.x;
    for (int i = tid; i < BINN * DCH; i += 512) xs[i] = 0.f;
    __syncthreads();
    int beg = binbase[bin], end = binbase[bin + 1];
    int w = tid >> 6, lane = tid & 63;
    scatter_edges(xs, rec, beg, end, w, lane >> 5, lane & 31, hbf);
    __syncthreads();
    int slot = tid >> 2, cq = tid & 3;
    int node0 = bin * BINN;
    int nn = min(BINN, n - node0);
    float v = 0.f;
    if (slot < nn) {
        int node = node0 + slot;
        float dc = dis[node];
        float tl = 2.f * dc;
        const unsigned* hs = hbf + (size_t)node * 32 + cq * 8;
        const float2* b2 = (const float2*)b;
        const float2* w2 = (const float2*)Wf;
        int rot = 2 * slot;
#pragma unroll
        for (int j = 0; j < 8; ++j) {
            unsigned hv = hs[j];
            int ch = cq * 16 + 2 * j;
            float x0 = xs[slot * DCH + ((ch + rot) & 63)]
                     + tl * __uint_as_float(hv << 16);
            float x1 = xs[slot * DCH + ((ch + 1 + rot) & 63)]
                     + tl * __uint_as_float(hv & 0xffff0000u);
            float2 bv = b2[cq * 8 + j];
            float2 wv = w2[cq * 8 + j];
            v += fmaxf(dc * x0 + bv.x, 0.f) * wv.x;
            v += fmaxf(dc * x1 + bv.y, 0.f) * wv.y;
        }
    }
    v += __shfl_xor(v, 1);
    v += __shfl_xor(v, 2);
    if (cq == 0 && slot < nn) out[node0 + slot] = v + bf[0];
}

extern "C" void kernel_launch(void* const* d_in, const int* in_sizes, int n_in,
                              void* d_out, int out_size, void* d_ws, size_t ws_size,
                              hipStream_t stream) {
    const float* x0 = (const float*)d_in[0];
    const int*   ei = (const int*)d_in[1];
    const float* ew = (const float*)d_in[2];
    const float* Ws = (const float*)d_in[3];
    const float* bs = (const float*)d_in[4];
    const float* Wf = (const float*)d_in[5];
    const float* bf = (const float*)d_in[6];

    const int n = in_sizes[0] / DCH;
    const int e = in_sizes[2];
    const int L = in_sizes[3] / (DCH * DCH);     // = 3

    const int* row = ei;        // edge_index[0] = source (gathered)
    const int* col = ei + e;    // edge_index[1] = target (aggregated)
    const int nbins = (n + BINN - 1) / BINN;     // 391 for n=50000 (<= 512)

    size_t off = 0;
    auto alloc = [&](size_t bytes) {
        off = (off + 255) & ~(size_t)255;
        void* r = (char*)d_ws + off;
        off += bytes;
        return r;
    };
    float*    dis     = (float*)   alloc((size_t)n * 4);
    short*    wpk     = (short*)   alloc((size_t)L * 2 * 512 * 8 * 2);
    uint2*    rec     = (uint2*)   alloc((size_t)e * 8);
    unsigned* blkcnt  = (unsigned*)alloc((size_t)NB_CSR * MAXBINS * 4);
    unsigned* blkcur  = (unsigned*)alloc((size_t)NB_CSR * MAXBINS * 4);
    unsigned* tot     = (unsigned*)alloc((size_t)MAXBINS * 4);
    int*      binbase = (int*)     alloc((size_t)(MAXBINS + 1) * 4);
    unsigned short* hb_a = (unsigned short*)alloc((size_t)2 * n * DCH * 2);
    unsigned short* hb_b = hb_a + (size_t)n * DCH;

    dim3 blk(256);
    const int n_tiles = (n + 15) / 16;

    // ---- bin-sort + norm + W pack ----
    binc_k   <<<dim3(NB_CSR), dim3(1024), 0, stream>>>(col, blkcnt, e);
    bincur1_k<<<dim3(nbins), dim3(64), 0, stream>>>(blkcnt, blkcur, tot);
    bincur2_k<<<dim3(1), dim3(512), 0, stream>>>(tot, binbase, nbins, e);
    binfill_k<<<dim3(NB_CSR), dim3(1024), 0, stream>>>(row, col, ew, blkcur, binbase, rec, e);
    deg_k    <<<dim3(nbins), dim3(512), 0, stream>>>(rec, binbase, dis, n);
    nfold_k  <<<dim3((e + 255) / 256), blk, 0, stream>>>(rec, dis, e);
    pack_k   <<<dim3((L * 512 + 255) / 256), blk, 0, stream>>>(Ws, wpk, L);

    // ---- layers (fused scatter + GEMM) ----
    const size_t wstride = (size_t)2 * 512 * 8;
    gemm_k<<<dim3((n_tiles + 3) / 4), blk, 0, stream>>>(x0, wpk, hb_a, n_tiles);
    sg_k  <<<dim3(nbins), dim3(512), 0, stream>>>(rec, binbase, dis, (const unsigned*)hb_a,
                                                  bs, wpk + wstride, hb_b, n);
    sg_k  <<<dim3(nbins), dim3(512), 0, stream>>>(rec, binbase, dis, (const unsigned*)hb_b,
                                                  bs + DCH, wpk + 2 * wstride, hb_a, n);
    sf_k  <<<dim3(nbins), dim3(512), 0, stream>>>(rec, binbase, dis, (const unsigned*)hb_a,
                                                  bs + 2 * DCH, Wf, bf, (float*)d_out, n);
}

// Round 4
// 235.562 us; speedup vs baseline: 7.4793x; 7.4793x over previous
//
#include <hip/hip_runtime.h>
#include <hip/hip_bf16.h>

#define DCH 64
#define NB_CSR 256          // edge-chunk blocks; chunk = ceil(e/256)
#define MAXBINS 256         // bins = ceil(n/256); n<=65536

typedef __attribute__((ext_vector_type(8))) short bfrag;   // 8 bf16
typedef __attribute__((ext_vector_type(4))) float ffrag;   // 4 fp32

static __device__ __forceinline__ unsigned short f2bf(float f) {
    unsigned u = __float_as_uint(f);
    unsigned r = (u + 0x7fffu + ((u >> 16) & 1u)) >> 16;   // RNE
    return (unsigned short)r;
}
static __device__ __forceinline__ float bf2f(unsigned short s) {
    return __uint_as_float(((unsigned)s) << 16);
}
static __device__ __forceinline__ float bf_lo(unsigned u) {
    return __uint_as_float(u << 16);
}
static __device__ __forceinline__ float bf_hi(unsigned u) {
    return __uint_as_float(u & 0xffff0000u);
}

// ---- CSR pass 1: per-block bin counts (bin = col>>8) ----
__global__ __launch_bounds__(1024) void binc_k(const int* __restrict__ col,
                                               unsigned* __restrict__ blkcnt, int e) {
    __shared__ unsigned bins[MAXBINS];
    int B = blockIdx.x, tid = threadIdx.x;
    int chunk = (e + NB_CSR - 1) / NB_CSR;
    int beg = B * chunk, end = min(e, beg + chunk);
    if (tid < MAXBINS) bins[tid] = 0;
    __syncthreads();
    for (int i = beg + tid; i < end; i += 1024)
        atomicAdd(&bins[col[i] >> 8], 1u);
    __syncthreads();
    if (tid < MAXBINS) blkcnt[B * MAXBINS + tid] = bins[tid];
}

// ---- CSR pass 2a (1 wave per bin): column prefix over the 256 chunk counts ----
__global__ __launch_bounds__(64) void bincur1_k(const unsigned* __restrict__ blkcnt,
                                                unsigned* __restrict__ blkcur,
                                                unsigned* __restrict__ tot) {
    int j = blockIdx.x, lane = threadIdx.x;
    unsigned carry = 0;
#pragma unroll
    for (int c = 0; c < NB_CSR; c += 64) {
        unsigned v = blkcnt[(size_t)(c + lane) * MAXBINS + j];
        unsigned s = v;
#pragma unroll
        for (int off = 1; off < 64; off <<= 1) {
            unsigned t = __shfl_up(s, off);
            if (lane >= off) s += t;
        }
        blkcur[(size_t)(c + lane) * MAXBINS + j] = carry + s - v;
        carry += __shfl(s, 63);
    }
    if (lane == 0) tot[j] = carry;
}

// ---- CSR pass 2b (1 block): exclusive scan of bin totals -> binbase ----
__global__ __launch_bounds__(256) void bincur2_k(const unsigned* __restrict__ tot,
                                                 int* __restrict__ binbase,
                                                 int* __restrict__ ptr,
                                                 int nbins, int n, int e) {
    __shared__ int wtot[4];
    int tid = threadIdx.x, lane = tid & 63, w = tid >> 6;
    int v = (tid < nbins) ? (int)tot[tid] : 0;
    int s = v;
#pragma unroll
    for (int off = 1; off < 64; off <<= 1) {
        int t = __shfl_up(s, off);
        if (lane >= off) s += t;
    }
    if (lane == 63) wtot[w] = s;
    __syncthreads();
    if (tid == 0) {
        int r = 0;
#pragma unroll
        for (int k = 0; k < 4; ++k) { int t = wtot[k]; wtot[k] = r; r += t; }
    }
    __syncthreads();
    int excl = s - v + wtot[w];
    if (tid < nbins) binbase[tid] = excl;
    if (tid == 0) { binbase[nbins] = e; ptr[n] = e; }
}

// ---- CSR pass 3: scatter packed records to bins (runs at block cursors) ----
__global__ __launch_bounds__(1024) void binfill_k(const int* __restrict__ row,
                                                  const int* __restrict__ col,
                                                  const float* __restrict__ ew,
                                                  const unsigned* __restrict__ blkcur,
                                                  const int* __restrict__ binbase,
                                                  uint2* __restrict__ rec, int e) {
    __shared__ unsigned cur[MAXBINS];
    int B = blockIdx.x, tid = threadIdx.x;
    int chunk = (e + NB_CSR - 1) / NB_CSR;
    int beg = B * chunk, end = min(e, beg + chunk);
    if (tid < MAXBINS) cur[tid] = blkcur[(size_t)B * MAXBINS + tid]
                                + (unsigned)binbase[tid];
    __syncthreads();
    for (int i = beg + tid; i < end; i += 1024) {
        int c = col[i];
        unsigned slot = atomicAdd(&cur[c >> 8], 1u);
        rec[slot] = make_uint2((unsigned)row[i] | ((unsigned)(c & 255) << 20),
                               __float_as_uint(ew[i]));
    }
}

// ---- CSR pass 4 (1 block per bin): node hist + ptr slice + fused deg/dis +
//      final placement into the bin's contiguous edg window (L2-local) ----
__global__ __launch_bounds__(1024) void csr_k(const uint2* __restrict__ rec,
                                              const int* __restrict__ binbase,
                                              int* __restrict__ ptr,
                                              uint2* __restrict__ edg,
                                              float* __restrict__ dis, int n) {
    __shared__ unsigned ncnt[256];
    __shared__ unsigned nbase[256];
    __shared__ float degs[256];
    int b = blockIdx.x, tid = threadIdx.x;
    int beg = binbase[b], end = binbase[b + 1];
    int node0 = b << 8;
    int nn = min(256, n - node0);
    if (tid < 256) { ncnt[tid] = 0; degs[tid] = 0.f; }
    __syncthreads();
    for (int i = beg + tid; i < end; i += 1024) {
        uint2 r = rec[i];
        unsigned c8 = r.x >> 20;
        atomicAdd(&ncnt[c8], 1u);
        atomicAdd(&degs[c8], __uint_as_float(r.y));
    }
    __syncthreads();
    // wave-0 shfl scan of the 256 per-node counts
    if (tid < 64) {
        unsigned carry = (unsigned)beg;
#pragma unroll
        for (int c = 0; c < 256; c += 64) {
            unsigned v = ncnt[c + tid];
            unsigned s = v;
#pragma unroll
            for (int off = 1; off < 64; off <<= 1) {
                unsigned t = __shfl_up(s, off);
                if (tid >= off) s += t;
            }
            nbase[c + tid] = carry + s - v;
            carry += __shfl(s, 63);
        }
    }
    __syncthreads();
    if (tid < nn) {
        ptr[node0 + tid] = (int)nbase[tid];
        dis[node0 + tid] = rsqrtf(degs[tid] + 2.0f);
    }
    if (tid < 256) ncnt[tid] = 0;
    __syncthreads();
    for (int i = beg + tid; i < end; i += 1024) {
        uint2 r = rec[i];
        unsigned c8 = r.x >> 20;
        unsigned pos = nbase[c8] + atomicAdd(&ncnt[c8], 1u);
        edg[pos] = make_uint2(r.x & 0xFFFFFu, r.y);
    }
}

// edg.y <- w * dis[src]  (fold source-side norm in once, for all layers)
__global__ __launch_bounds__(256) void normw_k(uint2* __restrict__ edg,
                                               const float* __restrict__ dis, int e) {
    int i = blockIdx.x * 256 + threadIdx.x;
    if (i >= e) return;
    uint2 ev = edg[i];
    ((unsigned*)edg)[2 * i + 1] =
        __float_as_uint(__uint_as_float(ev.y) * dis[ev.x]);
}

// Pack W (all L layers) into MFMA B-fragment layout, bf16 hi/lo split.
__global__ __launch_bounds__(256) void pack_k(const float* __restrict__ Ws,
                                              short* __restrict__ wpk, int L) {
    int ent = blockIdx.x * 256 + threadIdx.x;
    if (ent >= L * 512) return;
    int layer = ent >> 9;
    int r = ent & 511;
    int lane = r & 63;
    int st = r >> 6;
    int s = st >> 2, t = st & 3;
    int quad = lane >> 4;
    int ncol = t * 16 + (lane & 15);
    const float* W = Ws + (size_t)layer * DCH * DCH;
    union { short sh[8]; int4 v; } hi, lo;
#pragma unroll
    for (int j = 0; j < 8; ++j) {
        int k = s * 32 + quad * 8 + j;
        float w = W[k * DCH + ncol];
        unsigned short h = f2bf(w);
        hi.sh[j] = (short)h;
        lo.sh[j] = (short)f2bf(w - bf2f(h));
    }
    *(int4*)(wpk + ((size_t)(layer * 2 + 0) * 512 + r) * 8) = hi.v;
    *(int4*)(wpk + ((size_t)(layer * 2 + 1) * 512 + r) * 8) = lo.v;
}

// layer-0 GEMM: h = x0 @ W0 via bf16-split MFMA; output bf16.
__global__ __launch_bounds__(256) void gemm_k(const float* __restrict__ x,
                                              const short* __restrict__ wpk_layer,
                                              unsigned short* __restrict__ hb, int n_tiles) {
    __shared__ short Wl[2][512 * 8];
    {
        const int4* src = (const int4*)wpk_layer;
        int4* dst = (int4*)&Wl[0][0];
        for (int i = threadIdx.x; i < 1024; i += 256) dst[i] = src[i];
    }
    __syncthreads();
    int wave = threadIdx.x >> 6, lane = threadIdx.x & 63;
    int tile = blockIdx.x * 4 + wave;
    if (tile >= n_tiles) return;
    int m = lane & 15, quad = lane >> 4;
    int row = tile * 16 + m;

    float av[2][8];
    {
        const float4* p0 = (const float4*)(x + (size_t)row * DCH + quad * 8);
        const float4* p1 = (const float4*)(x + (size_t)row * DCH + 32 + quad * 8);
        float4 a0 = p0[0], a1 = p0[1], b0 = p1[0], b1 = p1[1];
        av[0][0] = a0.x; av[0][1] = a0.y; av[0][2] = a0.z; av[0][3] = a0.w;
        av[0][4] = a1.x; av[0][5] = a1.y; av[0][6] = a1.z; av[0][7] = a1.w;
        av[1][0] = b0.x; av[1][1] = b0.y; av[1][2] = b0.z; av[1][3] = b0.w;
        av[1][4] = b1.x; av[1][5] = b1.y; av[1][6] = b1.z; av[1][7] = b1.w;
    }
    bfrag ah[2], al[2];
#pragma unroll
    for (int s = 0; s < 2; ++s)
#pragma unroll
        for (int j = 0; j < 8; ++j) {
            unsigned short hbv = f2bf(av[s][j]);
            ah[s][j] = (short)hbv;
            al[s][j] = (short)f2bf(av[s][j] - bf2f(hbv));
        }

#pragma unroll
    for (int t = 0; t < 4; ++t) {
        ffrag acc = {0.f, 0.f, 0.f, 0.f};
#pragma unroll
        for (int s = 0; s < 2; ++s) {
            bfrag wh = *(bfrag*)&Wl[0][((s * 4 + t) * 64 + lane) * 8];
            bfrag wl = *(bfrag*)&Wl[1][((s * 4 + t) * 64 + lane) * 8];
            acc = __builtin_amdgcn_mfma_f32_16x16x32_bf16(ah[s], wh, acc, 0, 0, 0);
            acc = __builtin_amdgcn_mfma_f32_16x16x32_bf16(al[s], wh, acc, 0, 0, 0);
            acc = __builtin_amdgcn_mfma_f32_16x16x32_bf16(ah[s], wl, acc, 0, 0, 0);
        }
        int colc = t * 16 + m;
#pragma unroll
        for (int r = 0; r < 4; ++r)
            hb[(size_t)(tile * 16 + quad * 4 + r) * DCH + colc] = f2bf(acc[r]);
    }
}

// ---- gather core, group edition: 16 lanes per node; lane pp = channel quad
// (4pp..4pp+3, one dwordx2 of the 128B h-row). Each group walks its own edge
// list 8-deep pipelined, loading edg[e] group-uniformly: NO shfl, NO
// cross-lane folds, and a wave carries 4 fully independent node chains. ----
static __device__ __forceinline__ void gather_node16(int node, int pp,
                                                     float dis_c,
                                                     const int* __restrict__ ptr,
                                                     const uint2* __restrict__ edg,
                                                     const unsigned* __restrict__ hbf,
                                                     float a[4]) {
    int beg = ptr[node], end = ptr[node + 1];
    uint2 sv = *(const uint2*)(hbf + (size_t)node * 32 + 2 * pp);
    float wsl = 2.0f * dis_c;                    // improved self-loop weight
    a[0] = wsl * bf_lo(sv.x);
    a[1] = wsl * bf_hi(sv.x);
    a[2] = wsl * bf_lo(sv.y);
    a[3] = wsl * bf_hi(sv.y);
    for (int j0 = beg; j0 < end; j0 += 8) {
        uint2 rr[8];
#pragma unroll
        for (int q = 0; q < 8; ++q) {
            int e = j0 + q;
            rr[q] = (e < end) ? edg[e] : make_uint2(0u, 0u);  // pad: nv=0
        }
        uint2 hv[8];
#pragma unroll
        for (int q = 0; q < 8; ++q)
            hv[q] = *(const uint2*)(hbf + (size_t)rr[q].x * 32 + 2 * pp);
#pragma unroll
        for (int q = 0; q < 8; ++q) {
            float nn = __uint_as_float(rr[q].y);  // pre-folded w * dis[src]
            a[0] += bf_lo(hv[q].x) * nn;
            a[1] += bf_hi(hv[q].x) * nn;
            a[2] += bf_lo(hv[q].y) * nn;
            a[3] += bf_hi(hv[q].y) * nn;
        }
    }
}

// fused gather(l) + gemm(l+1): block = 4 waves = 16 nodes; each wave runs 4
// concurrent 16-lane node chains; activation tile in LDS (stride 68).
__global__ __launch_bounds__(256) void gg_k(const int* __restrict__ ptr,
                                            const uint2* __restrict__ edg,
                                            const float* __restrict__ dis,
                                            const unsigned* __restrict__ hbf,
                                            const float* __restrict__ b,
                                            const short* __restrict__ wpk_next,
                                            unsigned short* __restrict__ hb_out, int n) {
    __shared__ float xs[16][68];
    int w = threadIdx.x >> 6, lane = threadIdx.x & 63;
    int pp = lane & 15, sub = lane >> 4;
    int slot = w * 4 + sub;
    int tile = blockIdx.x;
    int node = tile * 16 + slot;
    if (node < n) {
        float dis_c = dis[node];
        float a[4];
        gather_node16(node, pp, dis_c, ptr, edg, hbf, a);
        float4 bv = ((const float4*)b)[pp];
        float4 o;
        o.x = fmaxf(dis_c * a[0] + bv.x, 0.f);
        o.y = fmaxf(dis_c * a[1] + bv.y, 0.f);
        o.z = fmaxf(dis_c * a[2] + bv.z, 0.f);
        o.w = fmaxf(dis_c * a[3] + bv.w, 0.f);
        *(float4*)&xs[slot][4 * pp] = o;         // row stride 272B, 16B-aligned
    }
    __syncthreads();
    // ---- GEMM phase: wave w = output col-group t ----
    int m = lane & 15, quad = lane >> 4, t = w;
    bfrag ah[2], al[2];
#pragma unroll
    for (int s = 0; s < 2; ++s)
#pragma unroll
        for (int j = 0; j < 8; ++j) {
            float v = xs[m][s * 32 + quad * 8 + j];
            unsigned short hbv = f2bf(v);
            ah[s][j] = (short)hbv;
            al[s][j] = (short)f2bf(v - bf2f(hbv));
        }
    ffrag acc = {0.f, 0.f, 0.f, 0.f};
#pragma unroll
    for (int s = 0; s < 2; ++s) {
        bfrag wh = *(const bfrag*)(wpk_next + ((size_t)((s * 4 + t) * 64 + lane)) * 8);
        bfrag wl = *(const bfrag*)(wpk_next + ((size_t)(512 + (s * 4 + t) * 64 + lane)) * 8);
        acc = __builtin_amdgcn_mfma_f32_16x16x32_bf16(ah[s], wh, acc, 0, 0, 0);
        acc = __builtin_amdgcn_mfma_f32_16x16x32_bf16(al[s], wh, acc, 0, 0, 0);
        acc = __builtin_amdgcn_mfma_f32_16x16x32_bf16(ah[s], wl, acc, 0, 0, 0);
    }
    int colc = t * 16 + m;
#pragma unroll
    for (int r = 0; r < 4; ++r) {
        int orow = tile * 16 + quad * 4 + r;
        if (orow < n) hb_out[(size_t)orow * DCH + colc] = f2bf(acc[r]);
    }
}

// fused gather(last) + final dot: out[node] = relu-agg(node) . Wf + bf
__global__ __launch_bounds__(256) void gf_k(const int* __restrict__ ptr,
                                            const uint2* __restrict__ edg,
                                            const float* __restrict__ dis,
                                            const unsigned* __restrict__ hbf,
                                            const float* __restrict__ b,
                                            const float* __restrict__ Wf,
                                            const float* __restrict__ bf,
                                            float* __restrict__ out, int n) {
    int lane = threadIdx.x & 63;
    int pp = lane & 15, sub = lane >> 4;
    int slot = (threadIdx.x >> 6) * 4 + sub;
    int node = blockIdx.x * 16 + slot;
    if (node >= n) return;
    float dis_c = dis[node];
    float a[4];
    gather_node16(node, pp, dis_c, ptr, edg, hbf, a);
    float4 bv = ((const float4*)b)[pp];
    float4 wv = ((const float4*)Wf)[pp];
    float v = fmaxf(dis_c * a[0] + bv.x, 0.f) * wv.x
            + fmaxf(dis_c * a[1] + bv.y, 0.f) * wv.y
            + fmaxf(dis_c * a[2] + bv.z, 0.f) * wv.z
            + fmaxf(dis_c * a[3] + bv.w, 0.f) * wv.w;
#pragma unroll
    for (int off = 8; off > 0; off >>= 1) v += __shfl_xor(v, off);  // fold 16 pp
    if (pp == 0) out[node] = v + bf[0];
}

extern "C" void kernel_launch(void* const* d_in, const int* in_sizes, int n_in,
                              void* d_out, int out_size, void* d_ws, size_t ws_size,
                              hipStream_t stream) {
    const float* x0 = (const float*)d_in[0];
    const int*   ei = (const int*)d_in[1];
    const float* ew = (const float*)d_in[2];
    const float* Ws = (const float*)d_in[3];
    const float* bs = (const float*)d_in[4];
    const float* Wf = (const float*)d_in[5];
    const float* bf = (const float*)d_in[6];

    const int n = in_sizes[0] / DCH;
    const int e = in_sizes[2];
    const int L = in_sizes[3] / (DCH * DCH);     // = 3

    const int* row = ei;        // edge_index[0] = source (gathered)
    const int* col = ei + e;    // edge_index[1] = target (aggregated)
    const int nbins = (n + 255) >> 8;            // 196 for n=50000 (must be <= 256)

    size_t off = 0;
    auto alloc = [&](size_t bytes) {
        off = (off + 255) & ~(size_t)255;
        void* r = (char*)d_ws + off;
        off += bytes;
        return r;
    };
    int*      ptr     = (int*)     alloc((size_t)(n + 1) * 4);
    float*    dis     = (float*)   alloc((size_t)n * 4);
    short*    wpk     = (short*)   alloc((size_t)L * 2 * 512 * 8 * 2);
    uint2*    edg     = (uint2*)   alloc((size_t)e * 8);
    unsigned* blkcnt  = (unsigned*)alloc((size_t)NB_CSR * MAXBINS * 4);
    unsigned* blkcur  = (unsigned*)alloc((size_t)NB_CSR * MAXBINS * 4);
    unsigned* tot     = (unsigned*)alloc((size_t)MAXBINS * 4);
    int*      binbase = (int*)     alloc((size_t)(MAXBINS + 1) * 4);
    // region A: rec (e uint2 = 10 MB) aliases TWO bf16 h buffers (12.8 MB);
    // rec is dead after csr_k, which precedes the first gemm write.
    size_t szR = (size_t)e * 8;
    size_t szH = (size_t)2 * n * DCH * 2;
    unsigned char* regA = (unsigned char*)alloc(szR > szH ? szR : szH);
    uint2* rec = (uint2*)regA;
    unsigned short* hb_a = (unsigned short*)regA;
    unsigned short* hb_b = hb_a + (size_t)n * DCH;

    dim3 blk(256);
    const int n_tiles = (n + 15) / 16;

    // ---- CSR build (bin sort) + norm + W pack ----
    binc_k   <<<dim3(NB_CSR), dim3(1024), 0, stream>>>(col, blkcnt, e);
    bincur1_k<<<dim3(nbins), dim3(64), 0, stream>>>(blkcnt, blkcur, tot);
    bincur2_k<<<dim3(1), blk, 0, stream>>>(tot, binbase, ptr, nbins, n, e);
    binfill_k<<<dim3(NB_CSR), dim3(1024), 0, stream>>>(row, col, ew, blkcur, binbase, rec, e);
    csr_k    <<<dim3(nbins), dim3(1024), 0, stream>>>(rec, binbase, ptr, edg, dis, n);
    normw_k  <<<dim3((e + 255) / 256), blk, 0, stream>>>(edg, dis, e);
    pack_k   <<<dim3((L * 512 + 255) / 256), blk, 0, stream>>>(Ws, wpk, L);

    // ---- layers (fused) ----
    const size_t wstride = (size_t)2 * 512 * 8;
    gemm_k<<<dim3((n_tiles + 3) / 4), blk, 0, stream>>>(x0, wpk, hb_a, n_tiles);
    gg_k  <<<dim3(n_tiles), blk, 0, stream>>>(ptr, edg, dis, (const unsigned*)hb_a,
                                              bs, wpk + wstride, hb_b, n);
    gg_k  <<<dim3(n_tiles), blk, 0, stream>>>(ptr, edg, dis, (const unsigned*)hb_b,
                                              bs + DCH, wpk + 2 * wstride, hb_a, n);
    gf_k  <<<dim3((n + 15) / 16), blk, 0, stream>>>(ptr, edg, dis, (const unsigned*)hb_a,
                                                    bs + 2 * DCH, Wf, bf, (float*)d_out, n);
}

// Round 5
// 230.298 us; speedup vs baseline: 7.6503x; 1.0229x over previous
//
#include <hip/hip_runtime.h>
#include <hip/hip_bf16.h>

#define DCH 64
#define NB_CSR 256          // edge-chunk blocks; chunk = ceil(e/256)
#define MAXBINS 256         // bins = ceil(n/256); n<=65536

typedef __attribute__((ext_vector_type(8))) short bfrag;   // 8 bf16
typedef __attribute__((ext_vector_type(4))) float ffrag;   // 4 fp32

static __device__ __forceinline__ unsigned short f2bf(float f) {
    unsigned u = __float_as_uint(f);
    unsigned r = (u + 0x7fffu + ((u >> 16) & 1u)) >> 16;   // RNE
    return (unsigned short)r;
}
static __device__ __forceinline__ float bf2f(unsigned short s) {
    return __uint_as_float(((unsigned)s) << 16);
}
static __device__ __forceinline__ float bf_lo(unsigned u) {
    return __uint_as_float(u << 16);
}
static __device__ __forceinline__ float bf_hi(unsigned u) {
    return __uint_as_float(u & 0xffff0000u);
}

// ---- CSR pass 1: per-block bin counts (bin = col>>8) ----
__global__ __launch_bounds__(1024) void binc_k(const int* __restrict__ col,
                                               unsigned* __restrict__ blkcnt, int e) {
    __shared__ unsigned bins[MAXBINS];
    int B = blockIdx.x, tid = threadIdx.x;
    int chunk = (e + NB_CSR - 1) / NB_CSR;
    int beg = B * chunk, end = min(e, beg + chunk);
    if (tid < MAXBINS) bins[tid] = 0;
    __syncthreads();
    for (int i = beg + tid; i < end; i += 1024)
        atomicAdd(&bins[col[i] >> 8], 1u);
    __syncthreads();
    if (tid < MAXBINS) blkcnt[B * MAXBINS + tid] = bins[tid];
}

// ---- CSR pass 2a (1 wave per bin): column prefix over the 256 chunk counts ----
__global__ __launch_bounds__(64) void bincur1_k(const unsigned* __restrict__ blkcnt,
                                                unsigned* __restrict__ blkcur,
                                                unsigned* __restrict__ tot) {
    int j = blockIdx.x, lane = threadIdx.x;
    unsigned carry = 0;
#pragma unroll
    for (int c = 0; c < NB_CSR; c += 64) {
        unsigned v = blkcnt[(size_t)(c + lane) * MAXBINS + j];
        unsigned s = v;
#pragma unroll
        for (int off = 1; off < 64; off <<= 1) {
            unsigned t = __shfl_up(s, off);
            if (lane >= off) s += t;
        }
        blkcur[(size_t)(c + lane) * MAXBINS + j] = carry + s - v;
        carry += __shfl(s, 63);
    }
    if (lane == 0) tot[j] = carry;
}

// ---- CSR pass 2b (1 block): exclusive scan of bin totals -> binbase ----
__global__ __launch_bounds__(256) void bincur2_k(const unsigned* __restrict__ tot,
                                                 int* __restrict__ binbase,
                                                 int* __restrict__ ptr,
                                                 int nbins, int n, int e) {
    __shared__ int wtot[4];
    int tid = threadIdx.x, lane = tid & 63, w = tid >> 6;
    int v = (tid < nbins) ? (int)tot[tid] : 0;
    int s = v;
#pragma unroll
    for (int off = 1; off < 64; off <<= 1) {
        int t = __shfl_up(s, off);
        if (lane >= off) s += t;
    }
    if (lane == 63) wtot[w] = s;
    __syncthreads();
    if (tid == 0) {
        int r = 0;
#pragma unroll
        for (int k = 0; k < 4; ++k) { int t = wtot[k]; wtot[k] = r; r += t; }
    }
    __syncthreads();
    int excl = s - v + wtot[w];
    if (tid < nbins) binbase[tid] = excl;
    if (tid == 0) { binbase[nbins] = e; ptr[n] = e; }
}

// ---- CSR pass 3: scatter packed records to bins (runs at block cursors) ----
__global__ __launch_bounds__(1024) void binfill_k(const int* __restrict__ row,
                                                  const int* __restrict__ col,
                                                  const float* __restrict__ ew,
                                                  const unsigned* __restrict__ blkcur,
                                                  const int* __restrict__ binbase,
                                                  uint2* __restrict__ rec, int e) {
    __shared__ unsigned cur[MAXBINS];
    int B = blockIdx.x, tid = threadIdx.x;
    int chunk = (e + NB_CSR - 1) / NB_CSR;
    int beg = B * chunk, end = min(e, beg + chunk);
    if (tid < MAXBINS) cur[tid] = blkcur[(size_t)B * MAXBINS + tid]
                                + (unsigned)binbase[tid];
    __syncthreads();
    for (int i = beg + tid; i < end; i += 1024) {
        int c = col[i];
        unsigned slot = atomicAdd(&cur[c >> 8], 1u);
        rec[slot] = make_uint2((unsigned)row[i] | ((unsigned)(c & 255) << 20),
                               __float_as_uint(ew[i]));
    }
}

// ---- CSR pass 4 (1 block per bin): node hist + ptr slice + fused deg/dis +
//      final placement into the bin's contiguous edg window (L2-local) ----
__global__ __launch_bounds__(1024) void csr_k(const uint2* __restrict__ rec,
                                              const int* __restrict__ binbase,
                                              int* __restrict__ ptr,
                                              uint2* __restrict__ edg,
                                              float* __restrict__ dis, int n) {
    __shared__ unsigned ncnt[256];
    __shared__ unsigned nbase[256];
    __shared__ float degs[256];
    int b = blockIdx.x, tid = threadIdx.x;
    int beg = binbase[b], end = binbase[b + 1];
    int node0 = b << 8;
    int nn = min(256, n - node0);
    if (tid < 256) { ncnt[tid] = 0; degs[tid] = 0.f; }
    __syncthreads();
    for (int i = beg + tid; i < end; i += 1024) {
        uint2 r = rec[i];
        unsigned c8 = r.x >> 20;
        atomicAdd(&ncnt[c8], 1u);
        atomicAdd(&degs[c8], __uint_as_float(r.y));
    }
    __syncthreads();
    // wave-0 shfl scan of the 256 per-node counts
    if (tid < 64) {
        unsigned carry = (unsigned)beg;
#pragma unroll
        for (int c = 0; c < 256; c += 64) {
            unsigned v = ncnt[c + tid];
            unsigned s = v;
#pragma unroll
            for (int off = 1; off < 64; off <<= 1) {
                unsigned t = __shfl_up(s, off);
                if (tid >= off) s += t;
            }
            nbase[c + tid] = carry + s - v;
            carry += __shfl(s, 63);
        }
    }
    __syncthreads();
    if (tid < nn) {
        ptr[node0 + tid] = (int)nbase[tid];
        dis[node0 + tid] = rsqrtf(degs[tid] + 2.0f);
    }
    if (tid < 256) ncnt[tid] = 0;
    __syncthreads();
    for (int i = beg + tid; i < end; i += 1024) {
        uint2 r = rec[i];
        unsigned c8 = r.x >> 20;
        unsigned pos = nbase[c8] + atomicAdd(&ncnt[c8], 1u);
        edg[pos] = make_uint2(r.x & 0xFFFFFu, r.y);
    }
}

// edg.y <- w * dis[src]  (fold source-side norm in once, for all layers)
__global__ __launch_bounds__(256) void normw_k(uint2* __restrict__ edg,
                                               const float* __restrict__ dis, int e) {
    int i = blockIdx.x * 256 + threadIdx.x;
    if (i >= e) return;
    uint2 ev = edg[i];
    ((unsigned*)edg)[2 * i + 1] =
        __float_as_uint(__uint_as_float(ev.y) * dis[ev.x]);
}

// Pack W (all L layers) into MFMA B-fragment layout, bf16 hi/lo split.
__global__ __launch_bounds__(256) void pack_k(const float* __restrict__ Ws,
                                              short* __restrict__ wpk, int L) {
    int ent = blockIdx.x * 256 + threadIdx.x;
    if (ent >= L * 512) return;
    int layer = ent >> 9;
    int r = ent & 511;
    int lane = r & 63;
    int st = r >> 6;
    int s = st >> 2, t = st & 3;
    int quad = lane >> 4;
    int ncol = t * 16 + (lane & 15);
    const float* W = Ws + (size_t)layer * DCH * DCH;
    union { short sh[8]; int4 v; } hi, lo;
#pragma unroll
    for (int j = 0; j < 8; ++j) {
        int k = s * 32 + quad * 8 + j;
        float w = W[k * DCH + ncol];
        unsigned short h = f2bf(w);
        hi.sh[j] = (short)h;
        lo.sh[j] = (short)f2bf(w - bf2f(h));
    }
    *(int4*)(wpk + ((size_t)(layer * 2 + 0) * 512 + r) * 8) = hi.v;
    *(int4*)(wpk + ((size_t)(layer * 2 + 1) * 512 + r) * 8) = lo.v;
}

// layer-0 GEMM: h = x0 @ W0 via bf16-split MFMA; output bf16.
__global__ __launch_bounds__(256) void gemm_k(const float* __restrict__ x,
                                              const short* __restrict__ wpk_layer,
                                              unsigned short* __restrict__ hb, int n_tiles) {
    __shared__ short Wl[2][512 * 8];
    {
        const int4* src = (const int4*)wpk_layer;
        int4* dst = (int4*)&Wl[0][0];
        for (int i = threadIdx.x; i < 1024; i += 256) dst[i] = src[i];
    }
    __syncthreads();
    int wave = threadIdx.x >> 6, lane = threadIdx.x & 63;
    int tile = blockIdx.x * 4 + wave;
    if (tile >= n_tiles) return;
    int m = lane & 15, quad = lane >> 4;
    int row = tile * 16 + m;

    float av[2][8];
    {
        const float4* p0 = (const float4*)(x + (size_t)row * DCH + quad * 8);
        const float4* p1 = (const float4*)(x + (size_t)row * DCH + 32 + quad * 8);
        float4 a0 = p0[0], a1 = p0[1], b0 = p1[0], b1 = p1[1];
        av[0][0] = a0.x; av[0][1] = a0.y; av[0][2] = a0.z; av[0][3] = a0.w;
        av[0][4] = a1.x; av[0][5] = a1.y; av[0][6] = a1.z; av[0][7] = a1.w;
        av[1][0] = b0.x; av[1][1] = b0.y; av[1][2] = b0.z; av[1][3] = b0.w;
        av[1][4] = b1.x; av[1][5] = b1.y; av[1][6] = b1.z; av[1][7] = b1.w;
    }
    bfrag ah[2], al[2];
#pragma unroll
    for (int s = 0; s < 2; ++s)
#pragma unroll
        for (int j = 0; j < 8; ++j) {
            unsigned short hbv = f2bf(av[s][j]);
            ah[s][j] = (short)hbv;
            al[s][j] = (short)f2bf(av[s][j] - bf2f(hbv));
        }

#pragma unroll
    for (int t = 0; t < 4; ++t) {
        ffrag acc = {0.f, 0.f, 0.f, 0.f};
#pragma unroll
        for (int s = 0; s < 2; ++s) {
            bfrag wh = *(bfrag*)&Wl[0][((s * 4 + t) * 64 + lane) * 8];
            bfrag wl = *(bfrag*)&Wl[1][((s * 4 + t) * 64 + lane) * 8];
            acc = __builtin_amdgcn_mfma_f32_16x16x32_bf16(ah[s], wh, acc, 0, 0, 0);
            acc = __builtin_amdgcn_mfma_f32_16x16x32_bf16(al[s], wh, acc, 0, 0, 0);
            acc = __builtin_amdgcn_mfma_f32_16x16x32_bf16(ah[s], wl, acc, 0, 0, 0);
        }
        int colc = t * 16 + m;
#pragma unroll
        for (int r = 0; r < 4; ++r)
            hb[(size_t)(tile * 16 + quad * 4 + r) * DCH + colc] = f2bf(acc[r]);
    }
}

// ---- gather core, dwordx4 edition: whole wave per node. lane = (oct, po):
// oct = lane>>3 is the edge slot (8 edges per wave-load), po = lane&7 is the
// 16B chunk of the 128B h-row (8 bf16 channels 8po..8po+7). One hbf wave-load
// covers 8 edges -> 8 lane-addresses/edge (was 32). Edge ids broadcast via
// shfl from the 64-edge window regs; fold over oct at the end (24 shfl/node).
static __device__ __forceinline__ void gather_node64(int node, int lane, int oct, int po,
                                                     float dis_c,
                                                     const int* __restrict__ ptr,
                                                     const uint2* __restrict__ edg,
                                                     const unsigned* __restrict__ hbf,
                                                     float a[8]) {
    if (oct == 0) {                               // self-loop term, added once
        uint4 sv = *(const uint4*)(hbf + (size_t)node * 32 + 4 * po);
        float wsl = 2.0f * dis_c;
        a[0] = wsl * bf_lo(sv.x); a[1] = wsl * bf_hi(sv.x);
        a[2] = wsl * bf_lo(sv.y); a[3] = wsl * bf_hi(sv.y);
        a[4] = wsl * bf_lo(sv.z); a[5] = wsl * bf_hi(sv.z);
        a[6] = wsl * bf_lo(sv.w); a[7] = wsl * bf_hi(sv.w);
    } else {
#pragma unroll
        for (int j = 0; j < 8; ++j) a[j] = 0.f;
    }
    int beg = ptr[node], end = ptr[node + 1];
    for (int base = beg; base < end; base += 64) {
        int idx = base + lane;
        int rv = 0; float nv = 0.f;
        if (idx < end) {
            uint2 ev = edg[idx];
            rv = (int)ev.x;
            nv = __uint_as_float(ev.y);          // pre-folded w * dis[src]
        }
        int m = min(64, end - base);
        int qn = (m + 7) >> 3;                   // 1..8 octets of edges
        for (int q0 = 0; q0 < qn; q0 += 4) {
            uint4 hv[4]; float nn[4];
#pragma unroll
            for (int u = 0; u < 4; ++u) {
                int eidx = 8 * (q0 + u) + oct;
                int r = __shfl(rv, eidx);        // padded lanes: r=0, nn=0
                nn[u] = __shfl(nv, eidx);
                hv[u] = *(const uint4*)(hbf + (size_t)r * 32 + 4 * po);
            }
#pragma unroll
            for (int u = 0; u < 4; ++u) {
                float w = nn[u];
                a[0] += bf_lo(hv[u].x) * w; a[1] += bf_hi(hv[u].x) * w;
                a[2] += bf_lo(hv[u].y) * w; a[3] += bf_hi(hv[u].y) * w;
                a[4] += bf_lo(hv[u].z) * w; a[5] += bf_hi(hv[u].z) * w;
                a[6] += bf_lo(hv[u].w) * w; a[7] += bf_hi(hv[u].w) * w;
            }
        }
    }
#pragma unroll
    for (int j = 0; j < 8; ++j) {                // fold the 8 edge slots
        a[j] += __shfl_xor(a[j], 8);
        a[j] += __shfl_xor(a[j], 16);
        a[j] += __shfl_xor(a[j], 32);
    }
}

// fused gather(l) + gemm(l+1): block = 4 waves = 16 nodes; wave does 4 serial
// nodes; activation tile in LDS (stride 68: 16B-aligned rows).
__global__ __launch_bounds__(256) void gg_k(const int* __restrict__ ptr,
                                            const uint2* __restrict__ edg,
                                            const float* __restrict__ dis,
                                            const unsigned* __restrict__ hbf,
                                            const float* __restrict__ b,
                                            const short* __restrict__ wpk_next,
                                            unsigned short* __restrict__ hb_out, int n) {
    __shared__ float xs[16][68];
    int w = threadIdx.x >> 6, lane = threadIdx.x & 63;
    int oct = lane >> 3, po = lane & 7;
    int tile = blockIdx.x;
#pragma unroll 1
    for (int i = 0; i < 4; ++i) {
        int node = tile * 16 + w * 4 + i;
        if (node < n) {
            float dis_c = dis[node];
            float a[8];
            gather_node64(node, lane, oct, po, dis_c, ptr, edg, hbf, a);
            if (oct == 0) {
                float4 b0 = ((const float4*)b)[2 * po];
                float4 b1 = ((const float4*)b)[2 * po + 1];
                float4 o0, o1;
                o0.x = fmaxf(dis_c * a[0] + b0.x, 0.f);
                o0.y = fmaxf(dis_c * a[1] + b0.y, 0.f);
                o0.z = fmaxf(dis_c * a[2] + b0.z, 0.f);
                o0.w = fmaxf(dis_c * a[3] + b0.w, 0.f);
                o1.x = fmaxf(dis_c * a[4] + b1.x, 0.f);
                o1.y = fmaxf(dis_c * a[5] + b1.y, 0.f);
                o1.z = fmaxf(dis_c * a[6] + b1.z, 0.f);
                o1.w = fmaxf(dis_c * a[7] + b1.w, 0.f);
                *(float4*)&xs[w * 4 + i][8 * po] = o0;     // 272B rows, 16B-aligned
                *(float4*)&xs[w * 4 + i][8 * po + 4] = o1;
            }
        }
    }
    __syncthreads();
    // ---- GEMM phase: wave w = output col-group t ----
    int m = lane & 15, quad = lane >> 4, t = w;
    bfrag ah[2], al[2];
#pragma unroll
    for (int s = 0; s < 2; ++s)
#pragma unroll
        for (int j = 0; j < 8; ++j) {
            float v = xs[m][s * 32 + quad * 8 + j];
            unsigned short hbv = f2bf(v);
            ah[s][j] = (short)hbv;
            al[s][j] = (short)f2bf(v - bf2f(hbv));
        }
    ffrag acc = {0.f, 0.f, 0.f, 0.f};
#pragma unroll
    for (int s = 0; s < 2; ++s) {
        bfrag wh = *(const bfrag*)(wpk_next + ((size_t)((s * 4 + t) * 64 + lane)) * 8);
        bfrag wl = *(const bfrag*)(wpk_next + ((size_t)(512 + (s * 4 + t) * 64 + lane)) * 8);
        acc = __builtin_amdgcn_mfma_f32_16x16x32_bf16(ah[s], wh, acc, 0, 0, 0);
        acc = __builtin_amdgcn_mfma_f32_16x16x32_bf16(al[s], wh, acc, 0, 0, 0);
        acc = __builtin_amdgcn_mfma_f32_16x16x32_bf16(ah[s], wl, acc, 0, 0, 0);
    }
    int colc = t * 16 + m;
#pragma unroll
    for (int r = 0; r < 4; ++r) {
        int orow = tile * 16 + quad * 4 + r;
        if (orow < n) hb_out[(size_t)orow * DCH + colc] = f2bf(acc[r]);
    }
}

// fused gather(last) + final dot: out[node] = relu-agg(node) . Wf + bf
__global__ __launch_bounds__(256) void gf_k(const int* __restrict__ ptr,
                                            const uint2* __restrict__ edg,
                                            const float* __restrict__ dis,
                                            const unsigned* __restrict__ hbf,
                                            const float* __restrict__ b,
                                            const float* __restrict__ Wf,
                                            const float* __restrict__ bf,
                                            float* __restrict__ out, int n) {
    int w = threadIdx.x >> 6, lane = threadIdx.x & 63;
    int oct = lane >> 3, po = lane & 7;
#pragma unroll 1
    for (int i = 0; i < 4; ++i) {
        int node = blockIdx.x * 16 + w * 4 + i;
        if (node >= n) continue;
        float dis_c = dis[node];
        float a[8];
        gather_node64(node, lane, oct, po, dis_c, ptr, edg, hbf, a);
        // after the oct-fold all lanes hold the same a[]; dot channel chunk po
        float4 b0 = ((const float4*)b)[2 * po];
        float4 b1 = ((const float4*)b)[2 * po + 1];
        float4 w0 = ((const float4*)Wf)[2 * po];
        float4 w1 = ((const float4*)Wf)[2 * po + 1];
        float v = fmaxf(dis_c * a[0] + b0.x, 0.f) * w0.x
                + fmaxf(dis_c * a[1] + b0.y, 0.f) * w0.y
                + fmaxf(dis_c * a[2] + b0.z, 0.f) * w0.z
                + fmaxf(dis_c * a[3] + b0.w, 0.f) * w0.w
                + fmaxf(dis_c * a[4] + b1.x, 0.f) * w1.x
                + fmaxf(dis_c * a[5] + b1.y, 0.f) * w1.y
                + fmaxf(dis_c * a[6] + b1.z, 0.f) * w1.z
                + fmaxf(dis_c * a[7] + b1.w, 0.f) * w1.w;
        v += __shfl_xor(v, 1);                   // fold the 8 po chunks
        v += __shfl_xor(v, 2);
        v += __shfl_xor(v, 4);
        if (lane == 0) out[node] = v + bf[0];
    }
}

extern "C" void kernel_launch(void* const* d_in, const int* in_sizes, int n_in,
                              void* d_out, int out_size, void* d_ws, size_t ws_size,
                              hipStream_t stream) {
    const float* x0 = (const float*)d_in[0];
    const int*   ei = (const int*)d_in[1];
    const float* ew = (const float*)d_in[2];
    const float* Ws = (const float*)d_in[3];
    const float* bs = (const float*)d_in[4];
    const float* Wf = (const float*)d_in[5];
    const float* bf = (const float*)d_in[6];

    const int n = in_sizes[0] / DCH;
    const int e = in_sizes[2];
    const int L = in_sizes[3] / (DCH * DCH);     // = 3

    const int* row = ei;        // edge_index[0] = source (gathered)
    const int* col = ei + e;    // edge_index[1] = target (aggregated)
    const int nbins = (n + 255) >> 8;            // 196 for n=50000 (must be <= 256)

    size_t off = 0;
    auto alloc = [&](size_t bytes) {
        off = (off + 255) & ~(size_t)255;
        void* r = (char*)d_ws + off;
        off += bytes;
        return r;
    };
    int*      ptr     = (int*)     alloc((size_t)(n + 1) * 4);
    float*    dis     = (float*)   alloc((size_t)n * 4);
    short*    wpk     = (short*)   alloc((size_t)L * 2 * 512 * 8 * 2);
    uint2*    edg     = (uint2*)   alloc((size_t)e * 8);
    unsigned* blkcnt  = (unsigned*)alloc((size_t)NB_CSR * MAXBINS * 4);
    unsigned* blkcur  = (unsigned*)alloc((size_t)NB_CSR * MAXBINS * 4);
    unsigned* tot     = (unsigned*)alloc((size_t)MAXBINS * 4);
    int*      binbase = (int*)     alloc((size_t)(MAXBINS + 1) * 4);
    // region A: rec (e uint2 = 10 MB) aliases TWO bf16 h buffers (12.8 MB);
    // rec is dead after csr_k, which precedes the first gemm write.
    size_t szR = (size_t)e * 8;
    size_t szH = (size_t)2 * n * DCH * 2;
    unsigned char* regA = (unsigned char*)alloc(szR > szH ? szR : szH);
    uint2* rec = (uint2*)regA;
    unsigned short* hb_a = (unsigned short*)regA;
    unsigned short* hb_b = hb_a + (size_t)n * DCH;

    dim3 blk(256);
    const int n_tiles = (n + 15) / 16;

    // ---- CSR build (bin sort) + norm + W pack ----
    binc_k   <<<dim3(NB_CSR), dim3(1024), 0, stream>>>(col, blkcnt, e);
    bincur1_k<<<dim3(nbins), dim3(64), 0, stream>>>(blkcnt, blkcur, tot);
    bincur2_k<<<dim3(1), blk, 0, stream>>>(tot, binbase, ptr, nbins, n, e);
    binfill_k<<<dim3(NB_CSR), dim3(1024), 0, stream>>>(row, col, ew, blkcur, binbase, rec, e);
    csr_k    <<<dim3(nbins), dim3(1024), 0, stream>>>(rec, binbase, ptr, edg, dis, n);
    normw_k  <<<dim3((e + 255) / 256), blk, 0, stream>>>(edg, dis, e);
    pack_k   <<<dim3((L * 512 + 255) / 256), blk, 0, stream>>>(Ws, wpk, L);

    // ---- layers (fused) ----
    const size_t wstride = (size_t)2 * 512 * 8;
    gemm_k<<<dim3((n_tiles + 3) / 4), blk, 0, stream>>>(x0, wpk, hb_a, n_tiles);
    gg_k  <<<dim3(n_tiles), blk, 0, stream>>>(ptr, edg, dis, (const unsigned*)hb_a,
                                              bs, wpk + wstride, hb_b, n);
    gg_k  <<<dim3(n_tiles), blk, 0, stream>>>(ptr, edg, dis, (const unsigned*)hb_b,
                                              bs + DCH, wpk + 2 * wstride, hb_a, n);
    gf_k  <<<dim3((n + 15) / 16), blk, 0, stream>>>(ptr, edg, dis, (const unsigned*)hb_a,
                                                    bs + 2 * DCH, Wf, bf, (float*)d_out, n);
}